// Round 1
// baseline (152.200 us; speedup 1.0000x reference)
//
#include <hip/hip_runtime.h>
#include <hip/hip_bf16.h>
#include <stdint.h>

using bf16   = __bf16;
using bf16x4 = __attribute__((ext_vector_type(4))) __bf16;
using bf16x8 = __attribute__((ext_vector_type(8))) __bf16;
using f32x4  = __attribute__((ext_vector_type(4))) float;

// geometry (fixed by the problem)
static constexpr int BATCH = 4, SEQ = 2048, DIM = 512, HEADS = 8, DK = 64;
static constexpr int M    = BATCH * SEQ;   // 8192 rows of x
static constexpr int NQKV = 3 * DIM;       // 1536
static constexpr int BHN  = BATCH * HEADS; // 32

#define GLD16(src, dst)                                                        \
    __builtin_amdgcn_global_load_lds(                                          \
        (const __attribute__((address_space(1))) void*)(src),                  \
        (__attribute__((address_space(3))) void*)(dst), 16, 0, 0)

// ---------------------------------------------------------------------------
// Kernel 1: convert x -> bf16, transpose-convert W [512][1536] -> Wt [1536][512],
// zero the S accumulator region (ws is re-poisoned to 0xAA before every launch).
// ---------------------------------------------------------------------------
__global__ __launch_bounds__(256) void k_prep(const float* __restrict__ x,
                                              const float* __restrict__ w,
                                              bf16* __restrict__ xbf,
                                              bf16* __restrict__ wt,
                                              float* __restrict__ S)
{
    const int bid = blockIdx.x;
    const int t   = threadIdx.x;
    const int XB  = (M * DIM) / (256 * 4);                 // 4096 blocks
    const int WB  = (DIM / 32) * (NQKV / 32);              // 16*48 = 768 blocks

    if (bid < XB) {
        const int i = (bid * 256 + t) * 4;
        float4 v = *(const float4*)(x + i);
        bf16x4 o = { (bf16)v.x, (bf16)v.y, (bf16)v.z, (bf16)v.w };
        *(bf16x4*)(xbf + i) = o;
    } else if (bid < XB + WB) {
        const int wb = bid - XB;
        const int rt = wb / 48, ct = wb - rt * 48;          // k-tile, n-tile
        __shared__ float tile[32][33];
        const int r = t >> 5, c = t & 31;                   // 8 rows x 32 cols, 4 passes
        #pragma unroll
        for (int i = 0; i < 4; ++i)
            tile[r + i * 8][c] = w[(rt * 32 + r + i * 8) * NQKV + ct * 32 + c];
        __syncthreads();
        #pragma unroll
        for (int i = 0; i < 4; ++i)
            wt[(ct * 32 + r + i * 8) * DIM + rt * 32 + c] = (bf16)tile[c][r + i * 8];
    } else {
        const int sb = bid - XB - WB;                       // 128 blocks
        const int i  = (sb * 256 + t) * 4;
        *(f32x4*)(S + i) = (f32x4){0.f, 0.f, 0.f, 0.f};
    }
}

// ---------------------------------------------------------------------------
// Kernel 2: qkv[8192][1536] fp32 = x_bf16[8192][512] @ W  (B given as Wt [n][k])
// 128x128 tile, BK=64, 4 waves (2x2), 16x16x32 bf16 MFMA.
// LDS tiles [128][64] bf16, XOR-swizzled ((row&7) on 16B chunks) realized by
// pre-swizzling the global source of global_load_lds (dest stays linear).
// ---------------------------------------------------------------------------
__global__ __launch_bounds__(256) void k_gemm(const bf16* __restrict__ A,
                                              const bf16* __restrict__ Bt,
                                              float* __restrict__ C)
{
    __shared__ bf16 sA[128 * 64];
    __shared__ bf16 sB[128 * 64];
    const int t    = threadIdx.x;
    const int lane = t & 63, wave = t >> 6;
    const int wm   = wave >> 1, wn = wave & 1;
    const int orig = blockIdx.x;                 // 768 blocks, 768 % 8 == 0
    const int wg   = (orig & 7) * 96 + (orig >> 3);  // XCD-contiguous chunks
    const int mt   = wg / 12, nt = wg - mt * 12;
    const int m0   = mt * 128, n0 = nt * 128;

    const int rl  = lane >> 3;                   // row within 8-row chunk
    const int cl  = (lane & 7) ^ rl;             // swizzled source 16B-chunk
    const int l15 = lane & 15, l4 = lane >> 4;

    f32x4 acc[4][4] = {};

    for (int k0 = 0; k0 < 512; k0 += 64) {
        #pragma unroll
        for (int i = 0; i < 4; ++i) {
            const int ch = wave * 4 + i;         // 16 x 1KB chunks per tile
            const int r  = ch * 8 + rl;          // tile row 0..127
            GLD16(A  + (m0 + r) * 512 + k0 + cl * 8, sA + ch * 512);
            GLD16(Bt + (n0 + r) * 512 + k0 + cl * 8, sB + ch * 512);
        }
        __syncthreads();
        #pragma unroll
        for (int kh = 0; kh < 2; ++kh) {
            bf16x8 af[4], bfv[4];
            const int rc = kh * 4 + l4;          // 16B chunk index within row
            #pragma unroll
            for (int mf = 0; mf < 4; ++mf) {
                const int row = wm * 64 + mf * 16 + l15;
                af[mf] = *(const bf16x8*)(sA + row * 64 + ((rc ^ (row & 7)) * 8));
            }
            #pragma unroll
            for (int nf = 0; nf < 4; ++nf) {
                const int row = wn * 64 + nf * 16 + l15;
                bfv[nf] = *(const bf16x8*)(sB + row * 64 + ((rc ^ (row & 7)) * 8));
            }
            #pragma unroll
            for (int mf = 0; mf < 4; ++mf)
                #pragma unroll
                for (int nf = 0; nf < 4; ++nf)
                    acc[mf][nf] = __builtin_amdgcn_mfma_f32_16x16x32_bf16(
                        af[mf], bfv[nf], acc[mf][nf], 0, 0, 0);
        }
        __syncthreads();
    }

    #pragma unroll
    for (int mf = 0; mf < 4; ++mf) {
        const int row0 = m0 + wm * 64 + mf * 16 + l4 * 4;
        #pragma unroll
        for (int nf = 0; nf < 4; ++nf) {
            const int col = n0 + wn * 64 + nf * 16 + l15;
            #pragma unroll
            for (int r = 0; r < 4; ++r)
                C[(row0 + r) * 1536 + col] = acc[mf][nf][r];
        }
    }
}

// ---------------------------------------------------------------------------
// Kernel 3: per-head LayerNorm of q,k (fp32 stats) + layout change.
//   qn  [bh][n][64] bf16 (row-major, MFMA A-operand for k_out)
//   ktr [bh][64][n] bf16 (transposed, MFMA B-operand for k_ktv)
//   vtr [bh][64][n] bf16 (transposed, MFMA A-operand for k_ktv)
// Block = (b,h, 64-row n-tile); thread t: row=t>>2, quarter q4=t&3 (16 lanes/d).
// ---------------------------------------------------------------------------
__global__ __launch_bounds__(256) void k_ln(const float* __restrict__ qkv,
                                            const float* __restrict__ gq,
                                            const float* __restrict__ bq,
                                            const float* __restrict__ gk,
                                            const float* __restrict__ bk,
                                            bf16* __restrict__ qn,
                                            bf16* __restrict__ ktr,
                                            bf16* __restrict__ vtr)
{
    __shared__ bf16 ks_[64 * 68];   // [64 rows][64 d] bf16, stride 68 (pad)
    __shared__ bf16 vs_[64 * 68];
    const int bid = blockIdx.x;
    const int nt = bid & 31, bh = bid >> 5;
    const int b = bh >> 3, h = bh & 7;
    const int t = threadIdx.x;
    const int row = t >> 2, q4 = t & 3;
    const long gRow = (long)b * SEQ + nt * 64 + row;
    const float* base = qkv + gRow * NQKV + h * 64 + q4 * 16;

    float v[16];

    // ---- Q: LN -> qn (row-major) ----
    #pragma unroll
    for (int i = 0; i < 4; ++i) *(float4*)(v + i * 4) = *(const float4*)(base + i * 4);
    {
        float s = 0.f, s2 = 0.f;
        #pragma unroll
        for (int i = 0; i < 16; ++i) { s += v[i]; s2 += v[i] * v[i]; }
        s  += __shfl_xor(s, 1);  s  += __shfl_xor(s, 2);
        s2 += __shfl_xor(s2, 1); s2 += __shfl_xor(s2, 2);
        const float mu = s * (1.f / 64.f);
        const float rs = rsqrtf(s2 * (1.f / 64.f) - mu * mu + 1e-5f);
        float gg[16], bb[16];
        #pragma unroll
        for (int i = 0; i < 4; ++i) {
            *(float4*)(gg + i * 4) = *(const float4*)(gq + h * 64 + q4 * 16 + i * 4);
            *(float4*)(bb + i * 4) = *(const float4*)(bq + h * 64 + q4 * 16 + i * 4);
        }
        bf16x8 o0, o1;
        #pragma unroll
        for (int i = 0; i < 8; ++i) o0[i] = (bf16)((v[i] - mu) * rs * gg[i] + bb[i]);
        #pragma unroll
        for (int i = 0; i < 8; ++i) o1[i] = (bf16)((v[8 + i] - mu) * rs * gg[8 + i] + bb[8 + i]);
        bf16* qdst = qn + ((long)bh * SEQ + nt * 64 + row) * 64 + q4 * 16;
        *(bf16x8*)(qdst)     = o0;
        *(bf16x8*)(qdst + 8) = o1;
    }

    // ---- K: LN -> LDS (row-major, transposed on the way out) ----
    #pragma unroll
    for (int i = 0; i < 4; ++i) *(float4*)(v + i * 4) = *(const float4*)(base + 512 + i * 4);
    {
        float s = 0.f, s2 = 0.f;
        #pragma unroll
        for (int i = 0; i < 16; ++i) { s += v[i]; s2 += v[i] * v[i]; }
        s  += __shfl_xor(s, 1);  s  += __shfl_xor(s, 2);
        s2 += __shfl_xor(s2, 1); s2 += __shfl_xor(s2, 2);
        const float mu = s * (1.f / 64.f);
        const float rs = rsqrtf(s2 * (1.f / 64.f) - mu * mu + 1e-5f);
        float gg[16], bb[16];
        #pragma unroll
        for (int i = 0; i < 4; ++i) {
            *(float4*)(gg + i * 4) = *(const float4*)(gk + h * 64 + q4 * 16 + i * 4);
            *(float4*)(bb + i * 4) = *(const float4*)(bk + h * 64 + q4 * 16 + i * 4);
        }
        #pragma unroll
        for (int i4 = 0; i4 < 4; ++i4) {
            bf16x4 p;
            #pragma unroll
            for (int c = 0; c < 4; ++c)
                p[c] = (bf16)((v[i4 * 4 + c] - mu) * rs * gg[i4 * 4 + c] + bb[i4 * 4 + c]);
            *(bf16x4*)(ks_ + row * 68 + q4 * 16 + i4 * 4) = p;
        }
    }

    // ---- V: passthrough -> LDS ----
    #pragma unroll
    for (int i = 0; i < 4; ++i) *(float4*)(v + i * 4) = *(const float4*)(base + 1024 + i * 4);
    #pragma unroll
    for (int i4 = 0; i4 < 4; ++i4) {
        bf16x4 p;
        #pragma unroll
        for (int c = 0; c < 4; ++c) p[c] = (bf16)v[i4 * 4 + c];
        *(bf16x4*)(vs_ + row * 68 + q4 * 16 + i4 * 4) = p;
    }
    __syncthreads();

    // ---- phase 2: 4x4 register-block transpose -> ktr/vtr ----
    const int g = t >> 4, nb = t & 15;   // d-quad 0..15, n-quad 0..15
    {
        bf16x4 a0 = *(const bf16x4*)(ks_ + (nb * 4 + 0) * 68 + g * 4);
        bf16x4 a1 = *(const bf16x4*)(ks_ + (nb * 4 + 1) * 68 + g * 4);
        bf16x4 a2 = *(const bf16x4*)(ks_ + (nb * 4 + 2) * 68 + g * 4);
        bf16x4 a3 = *(const bf16x4*)(ks_ + (nb * 4 + 3) * 68 + g * 4);
        #pragma unroll
        for (int c = 0; c < 4; ++c) {
            bf16x4 o = { a0[c], a1[c], a2[c], a3[c] };
            *(bf16x4*)(ktr + ((long)bh * 64 + g * 4 + c) * SEQ + nt * 64 + nb * 4) = o;
        }
    }
    {
        bf16x4 a0 = *(const bf16x4*)(vs_ + (nb * 4 + 0) * 68 + g * 4);
        bf16x4 a1 = *(const bf16x4*)(vs_ + (nb * 4 + 1) * 68 + g * 4);
        bf16x4 a2 = *(const bf16x4*)(vs_ + (nb * 4 + 2) * 68 + g * 4);
        bf16x4 a3 = *(const bf16x4*)(vs_ + (nb * 4 + 3) * 68 + g * 4);
        #pragma unroll
        for (int c = 0; c < 4; ++c) {
            bf16x4 o = { a0[c], a1[c], a2[c], a3[c] };
            *(bf16x4*)(vtr + ((long)bh * 64 + g * 4 + c) * SEQ + nt * 64 + nb * 4) = o;
        }
    }
}

// ---------------------------------------------------------------------------
// Kernel 4: S[bh][d'][d] = sum_n v[n][d'] * k[n][d]   (A=vtr rows, B=ktr rows)
// 32 bh x 8 n-splits = 256 blocks, 4 waves; each wave covers 64 n.
// Fragments loaded straight from global (wave touches 16 rows x 64B = coalesced).
// Block-level LDS reduce, then fp32 atomicAdd into S (zeroed by k_prep).
// ---------------------------------------------------------------------------
__global__ __launch_bounds__(256) void k_ktv(const bf16* __restrict__ ktr,
                                             const bf16* __restrict__ vtr,
                                             float* __restrict__ S)
{
    const int bid = blockIdx.x;
    const int bh = bid >> 3, ns = bid & 7;
    const int t = threadIdx.x, lane = t & 63, wave = t >> 6;
    const int l15 = lane & 15, l4 = lane >> 4;
    const int n0 = ns * 256 + wave * 64;
    const bf16* vb = vtr + (long)bh * 64 * SEQ;
    const bf16* kb = ktr + (long)bh * 64 * SEQ;

    f32x4 acc[4][4] = {};
    #pragma unroll
    for (int ks = 0; ks < 2; ++ks) {
        bf16x8 av[4], bk_[4];
        #pragma unroll
        for (int i = 0; i < 4; ++i) {
            av[i]  = *(const bf16x8*)(vb + (i * 16 + l15) * SEQ + n0 + ks * 32 + l4 * 8);
            bk_[i] = *(const bf16x8*)(kb + (i * 16 + l15) * SEQ + n0 + ks * 32 + l4 * 8);
        }
        #pragma unroll
        for (int i = 0; i < 4; ++i)
            #pragma unroll
            for (int j = 0; j < 4; ++j)
                acc[i][j] = __builtin_amdgcn_mfma_f32_16x16x32_bf16(av[i], bk_[j], acc[i][j], 0, 0, 0);
    }

    __shared__ float sred[4096];
    for (int i = t; i < 4096; i += 256) sred[i] = 0.f;
    __syncthreads();
    #pragma unroll
    for (int i = 0; i < 4; ++i)
        #pragma unroll
        for (int j = 0; j < 4; ++j)
            #pragma unroll
            for (int r = 0; r < 4; ++r) {
                const int dp = i * 16 + l4 * 4 + r;   // d'
                const int dd = j * 16 + l15;          // d
                atomicAdd(&sred[dp * 64 + dd], acc[i][j][r]);
            }
    __syncthreads();
    float* Sb = S + bh * 4096;
    for (int i = t; i < 4096; i += 256) atomicAdd(Sb + i, sred[i]);
}

// ---------------------------------------------------------------------------
// Kernel 5: out[b][n][h*64+d'] = 2^-14 * sum_d qn[bh][n][d] * S[bh][d'][d]
// 32 bh x 8 n-tiles(256) = 256 blocks, 4 waves x 64 rows.
// B-fragments built from fp32 S in-register (8 frags, loaded once per wave).
// ---------------------------------------------------------------------------
__global__ __launch_bounds__(256) void k_out(const bf16* __restrict__ qn,
                                             const float* __restrict__ S,
                                             float* __restrict__ out)
{
    const int bid = blockIdx.x;
    const int bh = bid >> 3, nt = bid & 7;
    const int b = bh >> 3, h = bh & 7;
    const int t = threadIdx.x, lane = t & 63, wave = t >> 6;
    const int l15 = lane & 15, l4 = lane >> 4;
    const float* Sb = S + bh * 4096;

    bf16x8 bfr[2][4];
    #pragma unroll
    for (int kh = 0; kh < 2; ++kh)
        #pragma unroll
        for (int cf = 0; cf < 4; ++cf) {
            const float* p = Sb + (cf * 16 + l15) * 64 + kh * 32 + l4 * 8;
            float4 lo = *(const float4*)(p);
            float4 hi = *(const float4*)(p + 4);
            bf16x8 f;
            f[0] = (bf16)lo.x; f[1] = (bf16)lo.y; f[2] = (bf16)lo.z; f[3] = (bf16)lo.w;
            f[4] = (bf16)hi.x; f[5] = (bf16)hi.y; f[6] = (bf16)hi.z; f[7] = (bf16)hi.w;
            bfr[kh][cf] = f;
        }

    const bf16* qb = qn + (long)bh * SEQ * 64;
    const int nbase = nt * 256 + wave * 64;
    const float scale = 1.f / 16384.f;   // (64^-0.5)/2048 exactly

    #pragma unroll
    for (int mf = 0; mf < 4; ++mf) {
        bf16x8 a0 = *(const bf16x8*)(qb + (nbase + mf * 16 + l15) * 64 +      l4 * 8);
        bf16x8 a1 = *(const bf16x8*)(qb + (nbase + mf * 16 + l15) * 64 + 32 + l4 * 8);
        f32x4 acc[4] = {};
        #pragma unroll
        for (int cf = 0; cf < 4; ++cf) {
            acc[cf] = __builtin_amdgcn_mfma_f32_16x16x32_bf16(a0, bfr[0][cf], acc[cf], 0, 0, 0);
            acc[cf] = __builtin_amdgcn_mfma_f32_16x16x32_bf16(a1, bfr[1][cf], acc[cf], 0, 0, 0);
        }
        #pragma unroll
        for (int cf = 0; cf < 4; ++cf)
            #pragma unroll
            for (int r = 0; r < 4; ++r) {
                const int n = nbase + mf * 16 + l4 * 4 + r;
                out[((long)b * SEQ + n) * 512 + h * 64 + cf * 16 + l15] = acc[cf][r] * scale;
            }
    }
}

// ---------------------------------------------------------------------------
extern "C" void kernel_launch(void* const* d_in, const int* in_sizes, int n_in,
                              void* d_out, int out_size, void* d_ws, size_t ws_size,
                              hipStream_t stream)
{
    const float* x  = (const float*)d_in[0];
    const float* w  = (const float*)d_in[1];
    const float* gq = (const float*)d_in[2];
    const float* bq = (const float*)d_in[3];
    const float* gk = (const float*)d_in[4];
    const float* bk = (const float*)d_in[5];
    float* out = (float*)d_out;

    char* ws = (char*)d_ws;
    // layout (bytes):
    //   qkv fp32 : 0         .. 50331648
    //   xbf bf16 : 50331648  .. +8388608   (reused as qn after k_gemm is done)
    //   wt  bf16 : 58720256  .. +1572864
    //   ktr bf16 : 60293120  .. +8388608
    //   vtr bf16 : 68681728  .. +8388608
    //   S   fp32 : 77070336  .. +524288    (total 77594624 B ~= 74 MB)
    float* qkv = (float*)(ws);
    bf16*  xbf = (bf16*)(ws + 50331648);
    bf16*  qn  = xbf;                       // overlay: xbf dead after k_gemm
    bf16*  wt  = (bf16*)(ws + 58720256);
    bf16*  ktr = (bf16*)(ws + 60293120);
    bf16*  vtr = (bf16*)(ws + 68681728);
    float* S   = (float*)(ws + 77070336);

    hipLaunchKernelGGL(k_prep, dim3(4096 + 768 + 128), dim3(256), 0, stream, x, w, xbf, wt, S);
    hipLaunchKernelGGL(k_gemm, dim3(768), dim3(256), 0, stream, xbf, wt, qkv);
    hipLaunchKernelGGL(k_ln,   dim3(1024), dim3(256), 0, stream, qkv, gq, bq, gk, bk, qn, ktr, vtr);
    hipLaunchKernelGGL(k_ktv,  dim3(256), dim3(256), 0, stream, ktr, vtr, S);
    hipLaunchKernelGGL(k_out,  dim3(256), dim3(256), 0, stream, qn, S, out);
}

// Round 2
// 143.959 us; speedup vs baseline: 1.0572x; 1.0572x over previous
//
#include <hip/hip_runtime.h>
#include <hip/hip_bf16.h>
#include <stdint.h>

using bf16   = __bf16;
using bf16x4 = __attribute__((ext_vector_type(4))) __bf16;
using bf16x8 = __attribute__((ext_vector_type(8))) __bf16;
using f32x4  = __attribute__((ext_vector_type(4))) float;

// geometry (fixed by the problem)
static constexpr int BATCH = 4, SEQ = 2048, DIM = 512, HEADS = 8, DK = 64;
static constexpr int M    = BATCH * SEQ;   // 8192 rows of x
static constexpr int NQKV = 3 * DIM;       // 1536

#define GLD16(src, dst)                                                        \
    __builtin_amdgcn_global_load_lds(                                          \
        (const __attribute__((address_space(1))) void*)(src),                  \
        (__attribute__((address_space(3))) void*)(dst), 16, 0, 0)

// ---------------------------------------------------------------------------
// Kernel 1: x -> bf16; W [512][1536] -> Wt [1536][512] bf16; zero S.
// ---------------------------------------------------------------------------
__global__ __launch_bounds__(256) void k_prep(const float* __restrict__ x,
                                              const float* __restrict__ w,
                                              bf16* __restrict__ xbf,
                                              bf16* __restrict__ wt,
                                              float* __restrict__ S)
{
    const int bid = blockIdx.x;
    const int t   = threadIdx.x;
    const int XB  = (M * DIM) / (256 * 4);                 // 4096 blocks
    const int WB  = (DIM / 32) * (NQKV / 32);              // 768 blocks

    if (bid < XB) {
        const int i = (bid * 256 + t) * 4;
        float4 v = *(const float4*)(x + i);
        bf16x4 o = { (bf16)v.x, (bf16)v.y, (bf16)v.z, (bf16)v.w };
        *(bf16x4*)(xbf + i) = o;
    } else if (bid < XB + WB) {
        const int wb = bid - XB;
        const int rt = wb / 48, ct = wb - rt * 48;          // k-tile, n-tile
        __shared__ float tile[32][33];
        const int r = t >> 5, c = t & 31;
        #pragma unroll
        for (int i = 0; i < 4; ++i)
            tile[r + i * 8][c] = w[(rt * 32 + r + i * 8) * NQKV + ct * 32 + c];
        __syncthreads();
        #pragma unroll
        for (int i = 0; i < 4; ++i)
            wt[(ct * 32 + r + i * 8) * DIM + rt * 32 + c] = (bf16)tile[c][r + i * 8];
    } else {
        const int sb = bid - XB - WB;                       // 128 blocks
        const int i  = (sb * 256 + t) * 4;
        *(f32x4*)(S + i) = (f32x4){0.f, 0.f, 0.f, 0.f};
    }
}

// ---------------------------------------------------------------------------
// Kernel 2 (fused): qkv GEMM + per-head LayerNorm(q,k) + layout change.
//   A [8192][512] bf16 (x), Bt [1536][512] bf16 (W^T).  128x128 tile, BK=64,
//   4 waves (2x2).  Each wave's 64x64 C-subtile = one head exactly:
//   nt 0-3 -> q (LN -> qn[bh][n][64]), 4-7 -> k (LN -> ktr[bh][64][n]),
//   8-11 -> v (cast -> vtr[bh][64][n]).  LN stats from fp32 accumulators.
//   Epilogue stages the wave tile into LDS ep_t[d][n] (pad 72), then:
//     k/v: row-contiguous b128 reads -> 128B-segment transposed stores
//     q  : 4x4 register transpose -> [n][d] stores
// ---------------------------------------------------------------------------
__global__ __launch_bounds__(256) void k_gemm(const bf16* __restrict__ A,
                                              const bf16* __restrict__ Bt,
                                              const float* __restrict__ gq,
                                              const float* __restrict__ bq,
                                              const float* __restrict__ gk,
                                              const float* __restrict__ bk,
                                              bf16* __restrict__ qn,
                                              bf16* __restrict__ ktr,
                                              bf16* __restrict__ vtr)
{
    __shared__ union {
        struct { bf16 A[128 * 64]; bf16 B[128 * 64]; } g;
        bf16 ep[4][64][72];          // [wave][d][n], pad 72 (b128-aligned rows)
    } u;

    const int t    = threadIdx.x;
    const int lane = t & 63, wave = t >> 6;
    const int wm   = wave >> 1, wn = wave & 1;
    const int orig = blockIdx.x;                     // 768 blocks, 768 % 8 == 0
    const int wg   = (orig & 7) * 96 + (orig >> 3);  // XCD-contiguous chunks
    const int mt   = wg / 12, nt = wg - mt * 12;
    const int m0   = mt * 128, n0 = nt * 128;

    const int rl  = lane >> 3;
    const int cl  = (lane & 7) ^ rl;                 // swizzled source chunk
    const int l15 = lane & 15, l4 = lane >> 4;

    f32x4 acc[4][4] = {};

    for (int k0 = 0; k0 < 512; k0 += 64) {
        #pragma unroll
        for (int i = 0; i < 4; ++i) {
            const int ch = wave * 4 + i;
            const int r  = ch * 8 + rl;
            GLD16(A  + (m0 + r) * 512 + k0 + cl * 8, u.g.A + ch * 512);
            GLD16(Bt + (n0 + r) * 512 + k0 + cl * 8, u.g.B + ch * 512);
        }
        __syncthreads();
        #pragma unroll
        for (int kh = 0; kh < 2; ++kh) {
            bf16x8 af[4], bfv[4];
            const int rc = kh * 4 + l4;
            #pragma unroll
            for (int mf = 0; mf < 4; ++mf) {
                const int row = wm * 64 + mf * 16 + l15;
                af[mf] = *(const bf16x8*)(u.g.A + row * 64 + ((rc ^ (row & 7)) * 8));
            }
            #pragma unroll
            for (int nf = 0; nf < 4; ++nf) {
                const int row = wn * 64 + nf * 16 + l15;
                bfv[nf] = *(const bf16x8*)(u.g.B + row * 64 + ((rc ^ (row & 7)) * 8));
            }
            #pragma unroll
            for (int mf = 0; mf < 4; ++mf)
                #pragma unroll
                for (int nf = 0; nf < 4; ++nf)
                    acc[mf][nf] = __builtin_amdgcn_mfma_f32_16x16x32_bf16(
                        af[mf], bfv[nf], acc[mf][nf], 0, 0, 0);
        }
        __syncthreads();   // last iter: all waves done reading g.A/g.B -> ep safe
    }

    // ---------------- fused epilogue ----------------
    const int sect = nt >> 2;                 // 0=q 1=k 2=v
    const int h    = (nt & 3) * 2 + wn;       // head covered by this wave
    const int b    = m0 >> 11;
    const int bh   = b * 8 + h;
    const int nwbase = (m0 & 2047) + wm * 64; // seq offset of wave's 64 rows

    if (sect < 2) {
        const float* gp = (sect == 0 ? gq : gk) + h * 64;
        const float* bp = (sect == 0 ? bq : bk) + h * 64;
        float gv[4], bv[4];
        #pragma unroll
        for (int nf = 0; nf < 4; ++nf) {
            gv[nf] = gp[nf * 16 + l15];
            bv[nf] = bp[nf * 16 + l15];
        }
        #pragma unroll
        for (int mf = 0; mf < 4; ++mf) {
            float mu[4], rs[4];
            #pragma unroll
            for (int r = 0; r < 4; ++r) {
                float s = 0.f, s2 = 0.f;
                #pragma unroll
                for (int nf = 0; nf < 4; ++nf) {
                    const float xv = acc[mf][nf][r];
                    s += xv; s2 += xv * xv;
                }
                s  += __shfl_xor(s, 1);  s  += __shfl_xor(s, 2);
                s  += __shfl_xor(s, 4);  s  += __shfl_xor(s, 8);
                s2 += __shfl_xor(s2, 1); s2 += __shfl_xor(s2, 2);
                s2 += __shfl_xor(s2, 4); s2 += __shfl_xor(s2, 8);
                mu[r] = s * (1.f / 64.f);
                rs[r] = rsqrtf(s2 * (1.f / 64.f) - mu[r] * mu[r] + 1e-5f);
            }
            #pragma unroll
            for (int nf = 0; nf < 4; ++nf) {
                bf16x4 pk;
                #pragma unroll
                for (int r = 0; r < 4; ++r)
                    pk[r] = (bf16)((acc[mf][nf][r] - mu[r]) * rs[r] * gv[nf] + bv[nf]);
                *(bf16x4*)(&u.ep[wave][nf * 16 + l15][mf * 16 + l4 * 4]) = pk;
            }
        }
    } else {
        #pragma unroll
        for (int mf = 0; mf < 4; ++mf)
            #pragma unroll
            for (int nf = 0; nf < 4; ++nf) {
                bf16x4 pk;
                #pragma unroll
                for (int r = 0; r < 4; ++r) pk[r] = (bf16)acc[mf][nf][r];
                *(bf16x4*)(&u.ep[wave][nf * 16 + l15][mf * 16 + l4 * 4]) = pk;
            }
    }
    // wave-local LDS RAW below; compiler orders via lgkmcnt (same object).

    if (sect == 0) {
        // 4x4 transpose: ep_t[d][n] -> qn[bh][n][d]
        bf16* dst = qn + ((long)bh * SEQ + nwbase) * 64;
        const int nq = lane & 15, dq2 = lane >> 4;
        #pragma unroll
        for (int j = 0; j < 4; ++j) {
            const int d0 = (j * 4 + dq2) * 4;
            bf16x4 a0 = *(const bf16x4*)(&u.ep[wave][d0 + 0][nq * 4]);
            bf16x4 a1 = *(const bf16x4*)(&u.ep[wave][d0 + 1][nq * 4]);
            bf16x4 a2 = *(const bf16x4*)(&u.ep[wave][d0 + 2][nq * 4]);
            bf16x4 a3 = *(const bf16x4*)(&u.ep[wave][d0 + 3][nq * 4]);
            #pragma unroll
            for (int c = 0; c < 4; ++c) {
                bf16x4 o = { a0[c], a1[c], a2[c], a3[c] };
                *(bf16x4*)(dst + (nq * 4 + c) * 64 + d0) = o;
            }
        }
    } else {
        // row-contiguous: ep_t[d][n] -> (ktr|vtr)[bh][d][nwbase..]
        bf16* dst = (sect == 1 ? ktr : vtr) + (long)bh * 64 * SEQ + nwbase;
        const int rr = lane >> 3, ch = lane & 7;
        #pragma unroll
        for (int g2 = 0; g2 < 8; ++g2) {
            const int d = g2 * 8 + rr;
            bf16x8 vv = *(const bf16x8*)(&u.ep[wave][d][ch * 8]);
            *(bf16x8*)(dst + (long)d * SEQ + ch * 8) = vv;
        }
    }
}

// ---------------------------------------------------------------------------
// Kernel 3: S[bh][d'][d] = sum_n v[n][d'] * k[n][d]   (A=vtr rows, B=ktr rows)
// 32 bh x 8 n-splits = 256 blocks, 4 waves; block LDS reduce + fp32 atomics.
// ---------------------------------------------------------------------------
__global__ __launch_bounds__(256) void k_ktv(const bf16* __restrict__ ktr,
                                             const bf16* __restrict__ vtr,
                                             float* __restrict__ S)
{
    const int bid = blockIdx.x;
    const int bh = bid >> 3, ns = bid & 7;
    const int t = threadIdx.x, lane = t & 63, wave = t >> 6;
    const int l15 = lane & 15, l4 = lane >> 4;
    const int n0 = ns * 256 + wave * 64;
    const bf16* vb = vtr + (long)bh * 64 * SEQ;
    const bf16* kb = ktr + (long)bh * 64 * SEQ;

    f32x4 acc[4][4] = {};
    #pragma unroll
    for (int ks = 0; ks < 2; ++ks) {
        bf16x8 av[4], bk_[4];
        #pragma unroll
        for (int i = 0; i < 4; ++i) {
            av[i]  = *(const bf16x8*)(vb + (i * 16 + l15) * SEQ + n0 + ks * 32 + l4 * 8);
            bk_[i] = *(const bf16x8*)(kb + (i * 16 + l15) * SEQ + n0 + ks * 32 + l4 * 8);
        }
        #pragma unroll
        for (int i = 0; i < 4; ++i)
            #pragma unroll
            for (int j = 0; j < 4; ++j)
                acc[i][j] = __builtin_amdgcn_mfma_f32_16x16x32_bf16(av[i], bk_[j], acc[i][j], 0, 0, 0);
    }

    __shared__ float sred[4096];
    for (int i = t; i < 4096; i += 256) sred[i] = 0.f;
    __syncthreads();
    #pragma unroll
    for (int i = 0; i < 4; ++i)
        #pragma unroll
        for (int j = 0; j < 4; ++j)
            #pragma unroll
            for (int r = 0; r < 4; ++r) {
                const int dp = i * 16 + l4 * 4 + r;   // d'
                const int dd = j * 16 + l15;          // d
                atomicAdd(&sred[dp * 64 + dd], acc[i][j][r]);
            }
    __syncthreads();
    float* Sb = S + bh * 4096;
    for (int i = t; i < 4096; i += 256) atomicAdd(Sb + i, sred[i]);
}

// ---------------------------------------------------------------------------
// Kernel 4: out[b][n][h*64+d'] = 2^-14 * sum_d qn[bh][n][d] * S[bh][d'][d]
// ---------------------------------------------------------------------------
__global__ __launch_bounds__(256) void k_out(const bf16* __restrict__ qn,
                                             const float* __restrict__ S,
                                             float* __restrict__ out)
{
    const int bid = blockIdx.x;
    const int bh = bid >> 3, nt = bid & 7;
    const int b = bh >> 3, h = bh & 7;
    const int t = threadIdx.x, lane = t & 63, wave = t >> 6;
    const int l15 = lane & 15, l4 = lane >> 4;
    const float* Sb = S + bh * 4096;

    bf16x8 bfr[2][4];
    #pragma unroll
    for (int kh = 0; kh < 2; ++kh)
        #pragma unroll
        for (int cf = 0; cf < 4; ++cf) {
            const float* p = Sb + (cf * 16 + l15) * 64 + kh * 32 + l4 * 8;
            float4 lo = *(const float4*)(p);
            float4 hi = *(const float4*)(p + 4);
            bf16x8 f;
            f[0] = (bf16)lo.x; f[1] = (bf16)lo.y; f[2] = (bf16)lo.z; f[3] = (bf16)lo.w;
            f[4] = (bf16)hi.x; f[5] = (bf16)hi.y; f[6] = (bf16)hi.z; f[7] = (bf16)hi.w;
            bfr[kh][cf] = f;
        }

    const bf16* qb = qn + (long)bh * SEQ * 64;
    const int nbase = nt * 256 + wave * 64;
    const float scale = 1.f / 16384.f;   // (64^-0.5)/2048 exactly

    #pragma unroll
    for (int mf = 0; mf < 4; ++mf) {
        bf16x8 a0 = *(const bf16x8*)(qb + (nbase + mf * 16 + l15) * 64 +      l4 * 8);
        bf16x8 a1 = *(const bf16x8*)(qb + (nbase + mf * 16 + l15) * 64 + 32 + l4 * 8);
        f32x4 acc[4] = {};
        #pragma unroll
        for (int cf = 0; cf < 4; ++cf) {
            acc[cf] = __builtin_amdgcn_mfma_f32_16x16x32_bf16(a0, bfr[0][cf], acc[cf], 0, 0, 0);
            acc[cf] = __builtin_amdgcn_mfma_f32_16x16x32_bf16(a1, bfr[1][cf], acc[cf], 0, 0, 0);
        }
        #pragma unroll
        for (int cf = 0; cf < 4; ++cf)
            #pragma unroll
            for (int r = 0; r < 4; ++r) {
                const int n = nbase + mf * 16 + l4 * 4 + r;
                out[((long)b * SEQ + n) * 512 + h * 64 + cf * 16 + l15] = acc[cf][r] * scale;
            }
    }
}

// ---------------------------------------------------------------------------
extern "C" void kernel_launch(void* const* d_in, const int* in_sizes, int n_in,
                              void* d_out, int out_size, void* d_ws, size_t ws_size,
                              hipStream_t stream)
{
    const float* x  = (const float*)d_in[0];
    const float* w  = (const float*)d_in[1];
    const float* gq = (const float*)d_in[2];
    const float* bq = (const float*)d_in[3];
    const float* gk = (const float*)d_in[4];
    const float* bk = (const float*)d_in[5];
    float* out = (float*)d_out;

    char* ws = (char*)d_ws;
    // layout (bytes):
    //   xbf bf16 : 0        .. 8388608
    //   wt  bf16 : 8388608  .. 9961472
    //   qn  bf16 : 9961472  .. 18350080
    //   ktr bf16 : 18350080 .. 26738688
    //   vtr bf16 : 26738688 .. 35127296
    //   S   fp32 : 35127296 .. 35651584   (~34 MB total)
    bf16*  xbf = (bf16*)(ws);
    bf16*  wt  = (bf16*)(ws + 8388608);
    bf16*  qn  = (bf16*)(ws + 9961472);
    bf16*  ktr = (bf16*)(ws + 18350080);
    bf16*  vtr = (bf16*)(ws + 26738688);
    float* S   = (float*)(ws + 35127296);

    hipLaunchKernelGGL(k_prep, dim3(4096 + 768 + 128), dim3(256), 0, stream, x, w, xbf, wt, S);
    hipLaunchKernelGGL(k_gemm, dim3(768), dim3(256), 0, stream,
                       xbf, wt, gq, bq, gk, bk, qn, ktr, vtr);
    hipLaunchKernelGGL(k_ktv,  dim3(256), dim3(256), 0, stream, ktr, vtr, S);
    hipLaunchKernelGGL(k_out,  dim3(256), dim3(256), 0, stream, qn, S, out);
}

// Round 3
// 125.524 us; speedup vs baseline: 1.2125x; 1.1469x over previous
//
#include <hip/hip_runtime.h>
#include <hip/hip_bf16.h>
#include <stdint.h>

using bf16   = __bf16;
using bf16x4 = __attribute__((ext_vector_type(4))) __bf16;
using bf16x8 = __attribute__((ext_vector_type(8))) __bf16;
using f32x4  = __attribute__((ext_vector_type(4))) float;

// geometry (fixed by the problem)
static constexpr int BATCH = 4, SEQ = 2048, DIM = 512, HEADS = 8, DK = 64;
static constexpr int M    = BATCH * SEQ;   // 8192 rows of x
static constexpr int NQKV = 3 * DIM;       // 1536

#define GLD16(src, dst)                                                        \
    __builtin_amdgcn_global_load_lds(                                          \
        (const __attribute__((address_space(1))) void*)(src),                  \
        (__attribute__((address_space(3))) void*)(dst), 16, 0, 0)

// ---------------------------------------------------------------------------
// Kernel 1 (tiny): W [512][1536] fp32 -> Wt [1536][512] bf16; zero S.
// ---------------------------------------------------------------------------
__global__ __launch_bounds__(256) void k_prep(const float* __restrict__ w,
                                              bf16* __restrict__ wt,
                                              float* __restrict__ S)
{
    const int bid = blockIdx.x;
    const int t   = threadIdx.x;
    const int WB  = (DIM / 32) * (NQKV / 32);              // 768 blocks

    if (bid < WB) {
        const int rt = bid / 48, ct = bid - rt * 48;        // k-tile, n-tile
        __shared__ float tile[32][33];
        const int r = t >> 5, c = t & 31;
        #pragma unroll
        for (int i = 0; i < 4; ++i)
            tile[r + i * 8][c] = w[(rt * 32 + r + i * 8) * NQKV + ct * 32 + c];
        __syncthreads();
        #pragma unroll
        for (int i = 0; i < 4; ++i)
            wt[(ct * 32 + r + i * 8) * DIM + rt * 32 + c] = (bf16)tile[c][r + i * 8];
    } else {
        const int sb = bid - WB;                            // 128 blocks
        const int i  = (sb * 256 + t) * 4;
        *(f32x4*)(S + i) = (f32x4){0.f, 0.f, 0.f, 0.f};
    }
}

// ---------------------------------------------------------------------------
// Kernel 2 (mega): per (m-tile 128, head h) block computes GEMM columns
// {q_h | k_h | v_h} (128x192, 6 waves of 64x64), then fused epilogue:
//   q-waves (ws=0): LN -> LDS transpose -> qn[bh][n][64] (bf16)
//   k-waves (ws=1): LN -> kst[d][128n] LDS (swizzled)
//   v-waves (ws=2): cast -> vst[d'][128n] LDS (swizzled)
//   barrier; v-waves then MFMA the block's partial S[d'][d] (K=128 rows)
//   and atomicAdd into global S[bh] (zeroed by k_prep).
// A is reg-staged from fp32 x (convert->swizzled ds_write); B via GLD16 of Wt.
// ---------------------------------------------------------------------------
__global__ __launch_bounds__(384) void k_gemm(const float* __restrict__ x,
                                              const bf16* __restrict__ Wt,
                                              const float* __restrict__ gq,
                                              const float* __restrict__ bq,
                                              const float* __restrict__ gk,
                                              const float* __restrict__ bk,
                                              bf16* __restrict__ qn,
                                              float* __restrict__ S)
{
    __shared__ union {
        struct { bf16 A[128 * 64]; bf16 B[192 * 64]; } g;          // 40 KB
        struct { bf16 q[2][64][72]; bf16 kst[64 * 128]; bf16 vst[64 * 128]; } e; // 50 KB
    } u;

    const int t    = threadIdx.x;
    const int lane = t & 63, wave = t >> 6;      // 6 waves
    const int wm   = wave & 1, ws = wave >> 1;   // row-half, section (q/k/v)
    const int orig = blockIdx.x;                 // 512 blocks, 512 % 8 == 0
    const int wg   = (orig & 7) * 64 + (orig >> 3);  // XCD-contiguous
    const int mt   = wg >> 3, h = wg & 7;
    const int m0   = mt * 128;

    const int l15 = lane & 15, l4 = lane >> 4;
    const int rl  = lane >> 3, cl = (lane & 7) ^ rl;   // swizzled GLD src chunk

    f32x4 acc[4][4] = {};

    for (int k0 = 0; k0 < 512; k0 += 64) {
        // ---- B staging: 24 x 1KB chunks via global_load_lds (4 per wave) ----
        #pragma unroll
        for (int i = 0; i < 4; ++i) {
            const int ch  = wave * 4 + i;        // 0..23
            const int sec = ch >> 3;             // 0=q 1=k 2=v
            const int r   = (ch & 7) * 8 + rl;   // row within section (0..63)
            GLD16(Wt + ((sec * 512 + h * 64 + r) * 512 + k0 + cl * 8),
                  u.g.B + ch * 512);
        }
        // ---- A staging: fp32 x -> bf16, swizzled ds_write ----
        for (int i = t; i < 2048; i += 384) {
            const int row = i >> 4, ch = i & 15;           // 16B fp32 chunks
            float4 v = *(const float4*)(x + (m0 + row) * 512 + k0 + ch * 4);
            bf16x4 o = { (bf16)v.x, (bf16)v.y, (bf16)v.z, (bf16)v.w };
            *(bf16x4*)(u.g.A + row * 64 + (((ch >> 1) ^ (row & 7)) * 8) + (ch & 1) * 4) = o;
        }
        __syncthreads();
        // ---- MFMA ----
        #pragma unroll
        for (int kh = 0; kh < 2; ++kh) {
            bf16x8 af[4], bfv[4];
            const int rc = kh * 4 + l4;
            #pragma unroll
            for (int mf = 0; mf < 4; ++mf) {
                const int row = wm * 64 + mf * 16 + l15;
                af[mf] = *(const bf16x8*)(u.g.A + row * 64 + ((rc ^ (row & 7)) * 8));
            }
            #pragma unroll
            for (int nf = 0; nf < 4; ++nf) {
                const int row = ws * 64 + nf * 16 + l15;   // 0..191
                bfv[nf] = *(const bf16x8*)(u.g.B + row * 64 + ((rc ^ (row & 7)) * 8));
            }
            #pragma unroll
            for (int mf = 0; mf < 4; ++mf)
                #pragma unroll
                for (int nf = 0; nf < 4; ++nf)
                    acc[mf][nf] = __builtin_amdgcn_mfma_f32_16x16x32_bf16(
                        af[mf], bfv[nf], acc[mf][nf], 0, 0, 0);
        }
        __syncthreads();
    }

    // ---------------- fused epilogue ----------------
    const int b  = m0 >> 11;
    const int bh = b * 8 + h;
    const int nwbase = (m0 & 2047) + wm * 64;    // seq offset of wave's 64 rows

    if (ws < 2) {
        // LayerNorm over d=64 (4 nf frags x 16 l15 lanes), stats from fp32 acc
        const float* gp = (ws == 0 ? gq : gk) + h * 64;
        const float* bp = (ws == 0 ? bq : bk) + h * 64;
        float gv[4], bv[4];
        #pragma unroll
        for (int nf = 0; nf < 4; ++nf) {
            gv[nf] = gp[nf * 16 + l15];
            bv[nf] = bp[nf * 16 + l15];
        }
        #pragma unroll
        for (int mf = 0; mf < 4; ++mf) {
            float mu[4], rs[4];
            #pragma unroll
            for (int r = 0; r < 4; ++r) {
                float s = 0.f, s2 = 0.f;
                #pragma unroll
                for (int nf = 0; nf < 4; ++nf) {
                    const float xv = acc[mf][nf][r];
                    s += xv; s2 += xv * xv;
                }
                s  += __shfl_xor(s, 1);  s  += __shfl_xor(s, 2);
                s  += __shfl_xor(s, 4);  s  += __shfl_xor(s, 8);
                s2 += __shfl_xor(s2, 1); s2 += __shfl_xor(s2, 2);
                s2 += __shfl_xor(s2, 4); s2 += __shfl_xor(s2, 8);
                mu[r] = s * (1.f / 64.f);
                rs[r] = rsqrtf(s2 * (1.f / 64.f) - mu[r] * mu[r] + 1e-5f);
            }
            #pragma unroll
            for (int nf = 0; nf < 4; ++nf) {
                bf16x4 pk;
                #pragma unroll
                for (int r = 0; r < 4; ++r)
                    pk[r] = (bf16)((acc[mf][nf][r] - mu[r]) * rs[r] * gv[nf] + bv[nf]);
                if (ws == 0) {
                    // qep[d][n] (pad 72)
                    *(bf16x4*)(&u.e.q[wm][nf * 16 + l15][mf * 16 + l4 * 4]) = pk;
                } else {
                    // kst[d][128n], 16B-chunk XOR swizzle by d&7
                    const int d = nf * 16 + l15;
                    const int c = wm * 8 + mf * 2 + (l4 >> 1);   // n-chunk 0..15
                    *(bf16x4*)(u.e.kst + d * 128 + ((c ^ (d & 7)) * 8) + (l4 & 1) * 4) = pk;
                }
            }
        }
    } else {
        // v: plain cast into vst[d'][128n], same swizzle
        #pragma unroll
        for (int mf = 0; mf < 4; ++mf)
            #pragma unroll
            for (int nf = 0; nf < 4; ++nf) {
                bf16x4 pk;
                #pragma unroll
                for (int r = 0; r < 4; ++r) pk[r] = (bf16)acc[mf][nf][r];
                const int d = nf * 16 + l15;
                const int c = wm * 8 + mf * 2 + (l4 >> 1);
                *(bf16x4*)(u.e.vst + d * 128 + ((c ^ (d & 7)) * 8) + (l4 & 1) * 4) = pk;
            }
    }

    if (ws == 0) {
        // wave-local 4x4 transpose qep[d][n] -> qn[bh][n][d]
        bf16* dst = qn + ((long)bh * SEQ + nwbase) * 64;
        const int nq = lane & 15, dq2 = lane >> 4;
        #pragma unroll
        for (int j = 0; j < 4; ++j) {
            const int d0 = (j * 4 + dq2) * 4;
            bf16x4 a0 = *(const bf16x4*)(&u.e.q[wm][d0 + 0][nq * 4]);
            bf16x4 a1 = *(const bf16x4*)(&u.e.q[wm][d0 + 1][nq * 4]);
            bf16x4 a2 = *(const bf16x4*)(&u.e.q[wm][d0 + 2][nq * 4]);
            bf16x4 a3 = *(const bf16x4*)(&u.e.q[wm][d0 + 3][nq * 4]);
            #pragma unroll
            for (int c = 0; c < 4; ++c) {
                bf16x4 o = { a0[c], a1[c], a2[c], a3[c] };
                *(bf16x4*)(dst + (nq * 4 + c) * 64 + d0) = o;
            }
        }
    }

    __syncthreads();   // kst/vst complete for all waves

    if (ws == 2) {
        // partial S[d'][d] over this block's 128 rows; wave wm does ks pair
        f32x4 sac[4][4] = {};
        #pragma unroll
        for (int kk = 0; kk < 2; ++kk) {
            const int ksi = wm * 2 + kk;          // 0..3 (n-chunk of 32)
            const int c   = ksi * 4 + l4;         // 16B chunk 0..15
            bf16x8 av[4], bk8[4];
            #pragma unroll
            for (int i = 0; i < 4; ++i) {
                const int dp = i * 16 + l15;
                av[i] = *(const bf16x8*)(u.e.vst + dp * 128 + ((c ^ (dp & 7)) * 8));
            }
            #pragma unroll
            for (int j = 0; j < 4; ++j) {
                const int dd = j * 16 + l15;
                bk8[j] = *(const bf16x8*)(u.e.kst + dd * 128 + ((c ^ (dd & 7)) * 8));
            }
            #pragma unroll
            for (int i = 0; i < 4; ++i)
                #pragma unroll
                for (int j = 0; j < 4; ++j)
                    sac[i][j] = __builtin_amdgcn_mfma_f32_16x16x32_bf16(
                        av[i], bk8[j], sac[i][j], 0, 0, 0);
        }
        float* Sb = S + bh * 4096;
        #pragma unroll
        for (int i = 0; i < 4; ++i)
            #pragma unroll
            for (int j = 0; j < 4; ++j)
                #pragma unroll
                for (int r = 0; r < 4; ++r) {
                    const int dp = i * 16 + l4 * 4 + r;   // d'
                    const int dd = j * 16 + l15;          // d
                    atomicAdd(Sb + dp * 64 + dd, sac[i][j][r]);
                }
    }
}

// ---------------------------------------------------------------------------
// Kernel 3: out[b][n][h*64+d'] = 2^-14 * sum_d qn[bh][n][d] * S[bh][d'][d]
// ---------------------------------------------------------------------------
__global__ __launch_bounds__(256) void k_out(const bf16* __restrict__ qn,
                                             const float* __restrict__ S,
                                             float* __restrict__ out)
{
    const int bid = blockIdx.x;
    const int bh = bid >> 3, nt = bid & 7;
    const int b = bh >> 3, h = bh & 7;
    const int t = threadIdx.x, lane = t & 63, wave = t >> 6;
    const int l15 = lane & 15, l4 = lane >> 4;
    const float* Sb = S + bh * 4096;

    bf16x8 bfr[2][4];
    #pragma unroll
    for (int kh = 0; kh < 2; ++kh)
        #pragma unroll
        for (int cf = 0; cf < 4; ++cf) {
            const float* p = Sb + (cf * 16 + l15) * 64 + kh * 32 + l4 * 8;
            float4 lo = *(const float4*)(p);
            float4 hi = *(const float4*)(p + 4);
            bf16x8 f;
            f[0] = (bf16)lo.x; f[1] = (bf16)lo.y; f[2] = (bf16)lo.z; f[3] = (bf16)lo.w;
            f[4] = (bf16)hi.x; f[5] = (bf16)hi.y; f[6] = (bf16)hi.z; f[7] = (bf16)hi.w;
            bfr[kh][cf] = f;
        }

    const bf16* qb = qn + (long)bh * SEQ * 64;
    const int nbase = nt * 256 + wave * 64;
    const float scale = 1.f / 16384.f;   // (64^-0.5)/2048 exactly

    #pragma unroll
    for (int mf = 0; mf < 4; ++mf) {
        bf16x8 a0 = *(const bf16x8*)(qb + (nbase + mf * 16 + l15) * 64 +      l4 * 8);
        bf16x8 a1 = *(const bf16x8*)(qb + (nbase + mf * 16 + l15) * 64 + 32 + l4 * 8);
        f32x4 acc[4] = {};
        #pragma unroll
        for (int cf = 0; cf < 4; ++cf) {
            acc[cf] = __builtin_amdgcn_mfma_f32_16x16x32_bf16(a0, bfr[0][cf], acc[cf], 0, 0, 0);
            acc[cf] = __builtin_amdgcn_mfma_f32_16x16x32_bf16(a1, bfr[1][cf], acc[cf], 0, 0, 0);
        }
        #pragma unroll
        for (int cf = 0; cf < 4; ++cf)
            #pragma unroll
            for (int r = 0; r < 4; ++r) {
                const int n = nbase + mf * 16 + l4 * 4 + r;
                out[((long)b * SEQ + n) * 512 + h * 64 + cf * 16 + l15] = acc[cf][r] * scale;
            }
    }
}

// ---------------------------------------------------------------------------
extern "C" void kernel_launch(void* const* d_in, const int* in_sizes, int n_in,
                              void* d_out, int out_size, void* d_ws, size_t ws_size,
                              hipStream_t stream)
{
    const float* x  = (const float*)d_in[0];
    const float* w  = (const float*)d_in[1];
    const float* gq = (const float*)d_in[2];
    const float* bq = (const float*)d_in[3];
    const float* gk = (const float*)d_in[4];
    const float* bk = (const float*)d_in[5];
    float* out = (float*)d_out;

    char* ws = (char*)d_ws;
    // layout (bytes):
    //   wt  bf16 : 0       .. 1572864
    //   qn  bf16 : 1572864 .. 9961472
    //   S   fp32 : 9961472 .. 10485760   (~10 MB total)
    bf16*  wt = (bf16*)(ws);
    bf16*  qn = (bf16*)(ws + 1572864);
    float* S  = (float*)(ws + 9961472);

    hipLaunchKernelGGL(k_prep, dim3(768 + 128), dim3(256), 0, stream, w, wt, S);
    hipLaunchKernelGGL(k_gemm, dim3(512), dim3(384), 0, stream,
                       x, wt, gq, bq, gk, bk, qn, S);
    hipLaunchKernelGGL(k_out,  dim3(256), dim3(256), 0, stream, qn, S, out);
}